// Round 8
// baseline (55856.024 us; speedup 1.0000x reference)
//
#include <hip/hip_runtime.h>

typedef unsigned short u16;
typedef unsigned int   u32;

// B=64, T=12, N=1024, DIN=2, HID=64, ED=10, K=2
// Full-f32 pipeline: the GRU recurrence amplifies perturbations ~x100 over the
// 24 serial cells, so NO bf16 anywhere on the recurrent path.

// ---------------------------------------------------------------------------
// A = softmax(relu(E E^T), axis=1); diagA[n]=A[n,n]. grid 1024, block 256
__global__ __launch_bounds__(256) void k_A2(const float* __restrict__ E,
    float* __restrict__ A, float* __restrict__ diagA)
{
  __shared__ float EL[10][1024];   // EL[e][m] = E[m][e]
  __shared__ float row[1024];
  __shared__ float red[4];
  int n = blockIdx.x, tid = threadIdx.x;
  for (int idx=tid; idx<10240; idx+=256)
    EL[idx>>10][idx&1023] = E[(idx&1023)*10 + (idx>>10)];
  __syncthreads();

  float en[10];
#pragma unroll
  for (int e=0;e<10;++e) en[e] = EL[e][n];

  float lmax = -1e30f;
#pragma unroll
  for (int j=0;j<4;++j){
    int m = tid*4 + j;
    float d = 0.f;
#pragma unroll
    for (int e=0;e<10;++e) d = fmaf(en[e], EL[e][m], d);
    d = fmaxf(d, 0.f);
    row[m] = d;
    lmax = fmaxf(lmax, d);
  }
#pragma unroll
  for (int o=32;o>0;o>>=1) lmax = fmaxf(lmax, __shfl_xor(lmax, o));
  if ((tid&63)==0) red[tid>>6] = lmax;
  __syncthreads();
  float mx = fmaxf(fmaxf(red[0],red[1]), fmaxf(red[2],red[3]));
  __syncthreads();

  float lsum = 0.f;
#pragma unroll
  for (int j=0;j<4;++j){
    int m = tid*4 + j;
    float ex = expf(row[m] - mx);
    row[m] = ex;
    lsum += ex;
  }
#pragma unroll
  for (int o=32;o>0;o>>=1) lsum += __shfl_xor(lsum, o);
  if ((tid&63)==0) red[tid>>6] = lsum;
  __syncthreads();
  float inv = 1.f/(red[0]+red[1]+red[2]+red[3]);

#pragma unroll
  for (int j=0;j<4;++j){
    int m = tid*4 + j;
    float v = row[m]*inv;
    A[(size_t)n*1024 + m] = v;
    if (m == n) diagA[n] = v;
  }
}

// ---------------------------------------------------------------------------
// b3eff[o] = b3[o] + sum_i b2[i]*(W3[o,i,0]+W3[o,i,1])   (1 block)
__global__ __launch_bounds__(64) void k_b3eff(
    const float* __restrict__ b2, const float* __restrict__ W3,
    const float* __restrict__ b3, float* __restrict__ b3eff)
{
  int o = threadIdx.x;
  if (o < 12){
    float a = b3[o];
    for (int i=0;i<12;++i)
      a += b2[i] * (W3[(o*12+i)*2] + W3[(o*12+i)*2+1]);
    b3eff[o] = a;
  }
}

// ---------------------------------------------------------------------------
// gemm2f: Y[slab][n][c] = sum_m A[n,m]*X[slab][m][c]   (f32 in/out)
// block 256, tile 64n x 64c, grid (16, 64)
__global__ __launch_bounds__(256) void gemm2f(const float* __restrict__ A,
    const float* __restrict__ X, float* __restrict__ Y)
{
  __shared__ float As[64][65];
  __shared__ float Xs[64][65];
  int n0 = blockIdx.x*64;
  long xb = (long)blockIdx.y * 65536, yb = (long)blockIdx.y * 65536;
  int tid = threadIdx.x, c = tid & 63, rq = tid >> 6;
  float acc[16];
#pragma unroll
  for (int j=0;j<16;++j) acc[j]=0.f;

  for (int m0=0; m0<1024; m0+=64){
#pragma unroll
    for (int j=0;j<16;++j){
      int idx = tid + j*256;
      int r = idx>>6, k = idx&63;
      As[r][k] = A[(size_t)(n0+r)*1024 + m0 + k];
      Xs[r][k] = X[xb + (long)(m0+r)*64 + k];
    }
    __syncthreads();
    for (int k=0;k<64;++k){
      float xv = Xs[k][c];
#pragma unroll
      for (int j=0;j<16;++j) acc[j] = fmaf(As[rq+4*j][k], xv, acc[j]);
    }
    __syncthreads();
  }
#pragma unroll
  for (int j=0;j<16;++j)
    Y[yb + (long)(n0+rq+4*j)*64 + c] = acc[j];
}

// ---------------------------------------------------------------------------
// gemm2x (fused x-gather): Ax0T[n][q] = sum_m A[n,m]*x[q>>1, m, q&1]
// q = (b*12+t)*2+c.  grid (16, 24), block 256.  f32 out.
__global__ __launch_bounds__(256) void gemm2x(const float* __restrict__ A,
    const float* __restrict__ x, float* __restrict__ Y)
{
  __shared__ float As[64][65];
  __shared__ float Xs[64][65];
  int n0 = blockIdx.x*64;
  int q0 = blockIdx.y*64;
  int tid = threadIdx.x, c = tid & 63, rq = tid >> 6;
  float acc[16];
#pragma unroll
  for (int j=0;j<16;++j) acc[j]=0.f;

  for (int m0=0; m0<1024; m0+=64){
#pragma unroll
    for (int j=0;j<16;++j){
      int idx = tid + j*256;
      int r = idx>>6, k = idx&63;
      As[r][k] = A[(size_t)(n0+r)*1024 + m0 + k];
      int qg = q0 + k;
      Xs[r][k] = x[(size_t)(qg>>1)*2048 + (size_t)(m0+r)*2 + (qg&1)];
    }
    __syncthreads();
    for (int k=0;k<64;++k){
      float xv = Xs[k][c];
#pragma unroll
      for (int j=0;j<16;++j) acc[j] = fmaf(As[rq+4*j][k], xv, acc[j]);
    }
    __syncthreads();
  }
#pragma unroll
  for (int j=0;j<16;++j)
    Y[(size_t)(n0+rq+4*j)*1536 + q0 + c] = acc[j];
}

// ---------------------------------------------------------------------------
// Gate (f32, on-the-fly weight combine): zr = sigmoid(b + W^T inp);
// zh = z*h (cols 0..63), rb = r (cols 64..127).
// grid (1024, 2), block 256.
// L=0: IX=2, KI=132, CH=66, xsrc=x.  L=1: IX=64, KI=256, CH=32, xsrc=h0.
template<int L>
__global__ __launch_bounds__(256) void k_gate_f(
    const float* __restrict__ Wg, const float* __restrict__ bgp,
    const float* __restrict__ E,
    const float* __restrict__ xsrc, const float* __restrict__ Axt,
    const float* __restrict__ h, const float* __restrict__ Ah,
    float* __restrict__ zh, float* __restrict__ rb, int t, int first)
{
  constexpr int IX  = (L==0)?2:64;
  constexpr int KI  = 2*(IX+64);
  constexpr int CH  = (L==0)?66:32;
  constexpr int NCH = KI/CH;
  constexpr int O   = 128;
  __shared__ float inp[32][KI];
  __shared__ float Wl[CH][O];
  __shared__ float En[10];
  int n = blockIdx.x, b0 = blockIdx.y*32, tid = threadIdx.x;

  if (tid < 10) En[tid] = E[n*10 + tid];
  for (int idx=tid; idx<32*IX; idx+=256){
    int bl = idx/IX, i = idx - bl*IX; int b = b0+bl;
    inp[bl][i] = (L==0)
      ? xsrc[(size_t)((b*12+t)*1024+n)*2 + i]
      : xsrc[((size_t)b<<16) + (size_t)n*64 + i];
  }
  for (int idx=tid; idx<2048; idx+=256){
    int bl = idx>>6, c = idx&63; int b = b0+bl;
    inp[bl][IX+c] = first ? 0.f : h[((size_t)b<<16) + (size_t)n*64 + c];
  }
  for (int idx=tid; idx<32*IX; idx+=256){
    int bl = idx/IX, i = idx - bl*IX; int b = b0+bl;
    inp[bl][IX+64+i] = (L==0)
      ? Axt[(size_t)n*1536 + (size_t)(b*12+t)*2 + i]
      : Axt[((size_t)b<<16) + (size_t)n*64 + i];
  }
  for (int idx=tid; idx<2048; idx+=256){
    int bl = idx>>6, c = idx&63; int b = b0+bl;
    inp[bl][2*IX+64+c] = first ? 0.f : Ah[((size_t)b<<16) + (size_t)n*64 + c];
  }
  __syncthreads();

  float acc[16];
#pragma unroll
  for (int j=0;j<16;++j){
    int o = (tid + j*256) & 127;
    float a = 0.f;
#pragma unroll
    for (int e=0;e<10;++e) a = fmaf(En[e], bgp[e*O + o], a);
    acc[j] = a;
  }

  for (int ch=0; ch<NCH; ++ch){
    for (int idx=tid; idx<CH*O; idx+=256){
      int i = idx>>7, o = idx&127;
      int row = ch*CH + i;
      float a = 0.f;
#pragma unroll
      for (int e=0;e<10;++e)
        a = fmaf(En[e], Wg[((size_t)e*KI + row)*O + o], a);
      Wl[i][o] = a;
    }
    __syncthreads();
#pragma unroll
    for (int j=0;j<16;++j){
      int w = tid + j*256;
      int bl = w>>7, o = w&127;
      float a = acc[j];
      const float* ip = &inp[bl][ch*CH];
#pragma unroll 4
      for (int i=0;i<CH;++i) a = fmaf(ip[i], Wl[i][o], a);
      acc[j] = a;
    }
    __syncthreads();
  }

#pragma unroll
  for (int j=0;j<16;++j){
    int w = tid + j*256;
    int bl = w>>7, o = w&127; int b = b0+bl;
    float s = 1.f/(1.f+__expf(-acc[j]));
    size_t base = ((size_t)b<<16) + (size_t)n*64;
    if (o < 64){
      if (!first) zh[base+o] = s * h[base+o];
    } else {
      rb[base+o-64] = s;
    }
  }
}

// ---------------------------------------------------------------------------
// Update (f32, on-the-fly weight combine): hc = tanh(b + W^T inp);
// h = r*h + (1-r)*hc.  grid (1024, 2), block 256.
// L=0: IX=2, KI=132, CH=66.  L=1: IX=64, KI=256, CH=64.
template<int L>
__global__ __launch_bounds__(256) void k_update_f(
    const float* __restrict__ Wu, const float* __restrict__ bup,
    const float* __restrict__ E,
    const float* __restrict__ xsrc, const float* __restrict__ Axt,
    const float* __restrict__ zh, const float* __restrict__ Azh,
    const float* __restrict__ rb, float* __restrict__ h, int t, int first)
{
  constexpr int IX  = (L==0)?2:64;
  constexpr int KI  = 2*(IX+64);
  constexpr int CH  = (L==0)?66:64;
  constexpr int NCH = KI/CH;
  constexpr int O   = 64;
  __shared__ float inp[32][KI];
  __shared__ float Wl[CH][O];
  __shared__ float En[10];
  int n = blockIdx.x, b0 = blockIdx.y*32, tid = threadIdx.x;

  if (tid < 10) En[tid] = E[n*10 + tid];
  for (int idx=tid; idx<32*IX; idx+=256){
    int bl = idx/IX, i = idx - bl*IX; int b = b0+bl;
    inp[bl][i] = (L==0)
      ? xsrc[(size_t)((b*12+t)*1024+n)*2 + i]
      : xsrc[((size_t)b<<16) + (size_t)n*64 + i];
  }
  for (int idx=tid; idx<2048; idx+=256){
    int bl = idx>>6, c = idx&63; int b = b0+bl;
    inp[bl][IX+c] = first ? 0.f : zh[((size_t)b<<16) + (size_t)n*64 + c];
  }
  for (int idx=tid; idx<32*IX; idx+=256){
    int bl = idx/IX, i = idx - bl*IX; int b = b0+bl;
    inp[bl][IX+64+i] = (L==0)
      ? Axt[(size_t)n*1536 + (size_t)(b*12+t)*2 + i]
      : Axt[((size_t)b<<16) + (size_t)n*64 + i];
  }
  for (int idx=tid; idx<2048; idx+=256){
    int bl = idx>>6, c = idx&63; int b = b0+bl;
    inp[bl][2*IX+64+c] = first ? 0.f : Azh[((size_t)b<<16) + (size_t)n*64 + c];
  }
  __syncthreads();

  float acc[8];
#pragma unroll
  for (int j=0;j<8;++j){
    int o = (tid + j*256) & 63;
    float a = 0.f;
#pragma unroll
    for (int e=0;e<10;++e) a = fmaf(En[e], bup[e*O + o], a);
    acc[j] = a;
  }

  for (int ch=0; ch<NCH; ++ch){
    for (int idx=tid; idx<CH*O; idx+=256){
      int i = idx>>6, o = idx&63;
      int row = ch*CH + i;
      float a = 0.f;
#pragma unroll
      for (int e=0;e<10;++e)
        a = fmaf(En[e], Wu[((size_t)e*KI + row)*O + o], a);
      Wl[i][o] = a;
    }
    __syncthreads();
#pragma unroll
    for (int j=0;j<8;++j){
      int w = tid + j*256;
      int bl = w>>6, o = w&63;
      float a = acc[j];
      const float* ip = &inp[bl][ch*CH];
#pragma unroll 4
      for (int i=0;i<CH;++i) a = fmaf(ip[i], Wl[i][o], a);
      acc[j] = a;
    }
    __syncthreads();
  }

#pragma unroll
  for (int j=0;j<8;++j){
    int w = tid + j*256;
    int bl = w>>6, o = w&63; int b = b0+bl;
    float hc = tanhf(acc[j]);
    size_t base = ((size_t)b<<16) + (size_t)n*64;
    float r   = rb[base+o];
    float h0v = first ? 0.f : h[base+o];
    h[base+o] = r*h0v + (1.f-r)*hc;
  }
}

// ---------------------------------------------------------------------------
// LITERAL q1: ol[b,n,c'] = sum_d h1[b,n,d]*W1[c',d];
//             q1acc[b,n,i] (+)= sum_c' W2[i,t,c'] * ol[b,n,c']
// grid (1024), block 256
__global__ __launch_bounds__(256) void k_q1_lit(const float* __restrict__ h1,
    const float* __restrict__ W1, const float* __restrict__ W2,
    float* __restrict__ q1acc, int t, int first)
{
  __shared__ float W1L[64][64];
  __shared__ float W2L[12][64];
  __shared__ float olL[8][64];
  int n = blockIdx.x, tid = threadIdx.x;
  for (int idx=tid; idx<4096; idx+=256)
    W1L[idx>>6][idx&63] = W1[idx];                 // W1L[c'][d]
  for (int idx=tid; idx<768; idx+=256)
    W2L[idx>>6][idx&63] = W2[((idx>>6)*12+t)*64 + (idx&63)];  // W2[i,t,c']
  __syncthreads();

  for (int b0=0; b0<64; b0+=8){
    for (int idx=tid; idx<512; idx+=256){
      int bl = idx>>6, c = idx&63; int b = b0+bl;
      const float* hv = h1 + ((size_t)b<<16) + (size_t)n*64;
      float s = 0.f;
#pragma unroll 8
      for (int d=0;d<64;++d) s = fmaf(hv[d], W1L[c][d], s);
      olL[bl][c] = s;
    }
    __syncthreads();
    if (tid < 96){
      int bl = tid/12, i = tid - (tid/12)*12; int b = b0+bl;
      float s = 0.f;
#pragma unroll 8
      for (int c=0;c<64;++c) s = fmaf(W2L[i][c], olL[bl][c], s);
      size_t qi = (((size_t)b<<10) + n)*12 + i;
      if (first) q1acc[qi] = s; else q1acc[qi] += s;
    }
    __syncthreads();
  }
}

// ---------------------------------------------------------------------------
// LITERAL q0: per (n, b): rg[12][128] -> conv Wc (width 65) -> rst[12][64]
//             -> q0buf[b,n,i] = sum_{j,w} W2[i,j,w]*rst[j][w]
// grid (1024, 64), block 256
__global__ __launch_bounds__(256) void k_q0_lit(
    const float* __restrict__ x, const float* __restrict__ diagA,
    const float* __restrict__ Wr, const float* __restrict__ br,
    const float* __restrict__ Wc, const float* __restrict__ W2,
    float* __restrict__ q0buf)
{
  __shared__ float rg[12][128];
  __shared__ float rst[12][64];
  int n = blockIdx.x, b = blockIdx.y, tid = threadIdx.x;
  float dA = diagA[n];

  for (int idx=tid; idx<768; idx+=256){
    int ip = idx>>6, c = idx&63;
    float x0 = x[(size_t)((b*12+ip)*1024+n)*2 + 0];
    float x1 = x[(size_t)((b*12+ip)*1024+n)*2 + 1];
    float rel = fmaf(x0, Wr[c*2], fmaf(x1, Wr[c*2+1], br[c]));
    rg[ip][2*c]   = rel;
    rg[ip][2*c+1] = rel * dA;
  }
  __syncthreads();

  for (int idx=tid; idx<768; idx+=256){
    int j = idx>>6, w = idx&63;
    float s = 0.f;
    for (int ip=0; ip<12; ++ip){
      const float* wc = Wc + (j*12+ip)*65;
      const float* rr = &rg[ip][w];
      for (int u=0; u<65; ++u) s = fmaf(wc[u], rr[u], s);
    }
    rst[j][w] = s;
  }
  __syncthreads();

  if (tid < 12){
    float s = 0.f;
    for (int j=0;j<12;++j){
      const float* w2r = W2 + (tid*12+j)*64;
      const float* rr  = rst[j];
      for (int w=0;w<64;++w) s = fmaf(w2r[w], rr[w], s);
    }
    q0buf[(((size_t)b<<10) + n)*12 + tid] = s;
  }
}

// ---------------------------------------------------------------------------
// Head combine: out[b,o,n] = b3eff[o] + sum_i q0*W3[o,i,0] + q1*W3[o,i,1]
// grid 1024, block 256
__global__ __launch_bounds__(256) void k_head2(
    const float* __restrict__ q0buf, const float* __restrict__ q1acc,
    const float* __restrict__ W3, const float* __restrict__ b3eff,
    float* __restrict__ out)
{
  int n = blockIdx.x, tid = threadIdx.x;
  __shared__ float W3L[12][12][2];
  __shared__ float b3eL[12];
  __shared__ float q0L[64][12];
  __shared__ float q1L[64][12];

  if (tid < 12) b3eL[tid] = b3eff[tid];
  for (int idx=tid; idx<288; idx+=256){
    int o = idx/24, r = idx - o*24;
    W3L[o][r>>1][r&1] = W3[idx];
  }
  for (int idx=tid; idx<768; idx+=256){
    int b = idx/12, i = idx - (idx/12)*12;
    size_t base = (((size_t)b<<10) + n)*12 + i;
    q0L[b][i] = q0buf[base];
    q1L[b][i] = q1acc[base];
  }
  __syncthreads();

  for (int idx=tid; idx<768; idx+=256){
    int bb = idx/12, o = idx - (idx/12)*12;
    float a = b3eL[o];
#pragma unroll
    for (int i=0;i<12;++i)
      a += q0L[bb][i]*W3L[o][i][0] + q1L[bb][i]*W3L[o][i][1];
    out[(size_t)(bb*12+o)*1024 + n] = a;
  }
}

// ---------------------------------------------------------------------------
extern "C" void kernel_launch(void* const* d_in, const int* in_sizes, int n_in,
                              void* d_out, int out_size, void* d_ws, size_t ws_size,
                              hipStream_t stream)
{
  const float* x   = (const float*)d_in[0];
  const float* E   = (const float*)d_in[1];
  const float* Wg0 = (const float*)d_in[2];
  const float* bg0 = (const float*)d_in[3];
  const float* Wu0 = (const float*)d_in[4];
  const float* bu0 = (const float*)d_in[5];
  const float* Wg1 = (const float*)d_in[6];
  const float* bg1 = (const float*)d_in[7];
  const float* Wu1 = (const float*)d_in[8];
  const float* bu1 = (const float*)d_in[9];
  const float* Wr  = (const float*)d_in[10];
  const float* br  = (const float*)d_in[11];
  const float* W1  = (const float*)d_in[12];
  const float* Wc  = (const float*)d_in[13];
  const float* W2  = (const float*)d_in[14];
  const float* b2  = (const float*)d_in[15];
  const float* W3  = (const float*)d_in[16];
  const float* b3  = (const float*)d_in[17];

  char* ws = (char*)d_ws;
  size_t off = 0;
  auto alloc = [&](size_t bytes)->void*{
    void* p = ws + off; off += (bytes + 255) & ~(size_t)255; return p;
  };
  float* A     = (float*)alloc(1024ull*1024*4);
  float* diagA = (float*)alloc(1024*4);
  float* Ax0T  = (float*)alloc(1024ull*1536*4);
  float* AhZ   = (float*)alloc(64ull*65536*4);
  float* zh    = (float*)alloc(64ull*65536*4);
  float* rb    = (float*)alloc(64ull*65536*4);
  float* Axt1  = (float*)alloc(64ull*65536*4);
  float* h0    = (float*)alloc(64ull*65536*4);
  float* h1    = (float*)alloc(64ull*65536*4);
  float* q1acc = (float*)alloc(64ull*1024*12*4);
  float* q0buf = (float*)alloc(64ull*1024*12*4);
  float* b3eff = (float*)alloc(12*4);

  if (off > ws_size) return;   // clean fail instead of fault

  // ---- precomputes ----
  k_A2<<<dim3(1024),256,0,stream>>>(E, A, diagA);
  k_b3eff<<<dim3(1),64,0,stream>>>(b2, W3, b3, b3eff);
  gemm2x<<<dim3(16,24),256,0,stream>>>(A, x, Ax0T);
  k_q0_lit<<<dim3(1024,64),256,0,stream>>>(x, diagA, Wr, br, Wc, W2, q0buf);

  for (int t=0;t<12;++t){
    int first = (t==0);
    // ---- layer 0 ----
    if (!first) gemm2f<<<dim3(16,64),256,0,stream>>>(A, h0, AhZ);
    k_gate_f<0><<<dim3(1024,2),256,0,stream>>>(Wg0, bg0, E, x, Ax0T, h0, AhZ,
                                               zh, rb, t, first);
    if (!first) gemm2f<<<dim3(16,64),256,0,stream>>>(A, zh, AhZ);
    k_update_f<0><<<dim3(1024,2),256,0,stream>>>(Wu0, bu0, E, x, Ax0T, zh, AhZ,
                                                 rb, h0, t, first);
    // ---- layer 1 (xt = h0_t) ----
    gemm2f<<<dim3(16,64),256,0,stream>>>(A, h0, Axt1);
    if (!first) gemm2f<<<dim3(16,64),256,0,stream>>>(A, h1, AhZ);
    k_gate_f<1><<<dim3(1024,2),256,0,stream>>>(Wg1, bg1, E, h0, Axt1, h1, AhZ,
                                               zh, rb, t, first);
    if (!first) gemm2f<<<dim3(16,64),256,0,stream>>>(A, zh, AhZ);
    k_update_f<1><<<dim3(1024,2),256,0,stream>>>(Wu1, bu1, E, h0, Axt1, zh, AhZ,
                                                 rb, h1, t, first);
    k_q1_lit<<<dim3(1024),256,0,stream>>>(h1, W1, W2, q1acc, t, first);
  }

  // ---- output head ----
  k_head2<<<dim3(1024),256,0,stream>>>(q0buf, q1acc, W3, b3eff, (float*)d_out);
}

// Round 9
// 10793.275 us; speedup vs baseline: 5.1751x; 5.1751x over previous
//
#include <hip/hip_runtime.h>

typedef unsigned short u16;
typedef unsigned int   u32;

// B=64, T=12, N=1024, DIN=2, HID=64, ED=10, K=2
// f32 recurrence throughout (bf16 on the recurrent path amplifies ~x100).
__device__ __forceinline__ float bf2f(u16 u){ return __uint_as_float(((u32)u)<<16); }
__device__ __forceinline__ u16 f2bf(float f){
  u32 u = __float_as_uint(f);
  return (u16)((u + 0x7fffu + ((u>>16)&1u)) >> 16);
}

// ---------------------------------------------------------------------------
// A = softmax(relu(E E^T), axis=1); diagA[n]=A[n,n]. grid 1024, block 256
__global__ __launch_bounds__(256) void k_A2(const float* __restrict__ E,
    float* __restrict__ A, float* __restrict__ diagA)
{
  __shared__ float EL[10][1024];
  __shared__ float row[1024];
  __shared__ float red[4];
  int n = blockIdx.x, tid = threadIdx.x;
  for (int idx=tid; idx<10240; idx+=256)
    EL[idx>>10][idx&1023] = E[(idx&1023)*10 + (idx>>10)];
  __syncthreads();
  float en[10];
#pragma unroll
  for (int e=0;e<10;++e) en[e] = EL[e][n];
  float lmax = -1e30f;
#pragma unroll
  for (int j=0;j<4;++j){
    int m = tid*4 + j;
    float d = 0.f;
#pragma unroll
    for (int e=0;e<10;++e) d = fmaf(en[e], EL[e][m], d);
    d = fmaxf(d, 0.f);
    row[m] = d; lmax = fmaxf(lmax, d);
  }
#pragma unroll
  for (int o=32;o>0;o>>=1) lmax = fmaxf(lmax, __shfl_xor(lmax, o));
  if ((tid&63)==0) red[tid>>6] = lmax;
  __syncthreads();
  float mx = fmaxf(fmaxf(red[0],red[1]), fmaxf(red[2],red[3]));
  __syncthreads();
  float lsum = 0.f;
#pragma unroll
  for (int j=0;j<4;++j){
    int m = tid*4 + j;
    float ex = expf(row[m] - mx);
    row[m] = ex; lsum += ex;
  }
#pragma unroll
  for (int o=32;o>0;o>>=1) lsum += __shfl_xor(lsum, o);
  if ((tid&63)==0) red[tid>>6] = lsum;
  __syncthreads();
  float inv = 1.f/(red[0]+red[1]+red[2]+red[3]);
#pragma unroll
  for (int j=0;j<4;++j){
    int m = tid*4 + j;
    float v = row[m]*inv;
    A[(size_t)n*1024 + m] = v;
    if (m == n) diagA[n] = v;
  }
}

// ---------------------------------------------------------------------------
// b3eff[o] = b3[o] + sum_i b2[i]*(W3[o,i,0]+W3[o,i,1])
__global__ __launch_bounds__(64) void k_b3eff(
    const float* __restrict__ b2, const float* __restrict__ W3,
    const float* __restrict__ b3, float* __restrict__ b3eff)
{
  int o = threadIdx.x;
  if (o < 12){
    float a = b3[o];
    for (int i=0;i<12;++i)
      a += b2[i] * (W3[(o*12+i)*2] + W3[(o*12+i)*2+1]);
    b3eff[o] = a;
  }
}

// ---------------------------------------------------------------------------
// V[i,j,c] = sum_o W2[i,j,o]*W1[o,c]  (f32)  grid 36, block 256
__global__ __launch_bounds__(256) void k_Vpre(const float* __restrict__ W1,
    const float* __restrict__ W2, float* __restrict__ V)
{
  int idx = blockIdx.x*256 + threadIdx.x;      // < 9216
  if (idx >= 9216) return;
  int c = idx & 63, r = idx >> 6;
  int j = r % 12, i = r / 12;
  float a = 0.f;
  for (int o=0;o<64;++o)
    a = fmaf(W2[(i*12+j)*64+o], W1[o*64+c], a);
  V[idx] = a;
}

// ---------------------------------------------------------------------------
// G[i,ip,u] = sum_j sum_w W2[i,j,w]*Wc[j,ip,u-w]  (bf16)  grid 72, block 256
__global__ __launch_bounds__(256) void k_Gpre(const float* __restrict__ Wc,
    const float* __restrict__ W2, u16* __restrict__ G)
{
  int idx = blockIdx.x*256 + threadIdx.x;      // < 18432
  int u = idx & 127, r = idx >> 7;
  int ip = r % 12, i = r / 12;
  float a = 0.f;
  int wlo = u>64 ? u-64 : 0;
  int whi = u<63 ? u : 63;
  for (int j=0;j<12;++j){
    const float* w2r = W2 + (i*12+j)*64;
    const float* wcr = Wc + (j*12+ip)*65;
    for (int w=wlo; w<=whi; ++w)
      a = fmaf(w2r[w], wcr[u-w], a);
  }
  G[idx] = f2bf(a);
}

// ---------------------------------------------------------------------------
// gemm3f: Y[s][n][c] = sum_m A[n,m]*X[s][m][c]  (f32, 128x64 tile, 8x4/thread)
// grid (8, 64), block 256
__global__ __launch_bounds__(256) void gemm3f(const float* __restrict__ A,
    const float* __restrict__ X, float* __restrict__ Y)
{
  int n0 = blockIdx.x * 128;
  long base = (long)blockIdx.y * 65536;
  __shared__ float At[16][132];
  __shared__ float Xt[16][64];
  int tid = threadIdx.x;
  int tx = tid & 15, ty = tid >> 4;
  float acc[8][4];
#pragma unroll
  for (int r=0;r<8;++r){ acc[r][0]=0;acc[r][1]=0;acc[r][2]=0;acc[r][3]=0; }

  for (int m0=0; m0<1024; m0+=16){
    {
      int r = tid>>1, kh = (tid&1)*8;
      const float* ap = A + (size_t)(n0+r)*1024 + m0 + kh;
      float4 q0 = *(const float4*)ap;
      float4 q1 = *(const float4*)(ap+4);
      At[kh+0][r]=q0.x; At[kh+1][r]=q0.y; At[kh+2][r]=q0.z; At[kh+3][r]=q0.w;
      At[kh+4][r]=q1.x; At[kh+5][r]=q1.y; At[kh+6][r]=q1.z; At[kh+7][r]=q1.w;
    }
    {
      int c = tid & 63, kq = tid >> 6;
#pragma unroll
      for (int j=0;j<4;++j)
        Xt[kq*4+j][c] = X[base + (long)(m0+kq*4+j)*64 + c];
    }
    __syncthreads();
#pragma unroll
    for (int kk=0;kk<16;++kk){
      float4 xv = *(const float4*)&Xt[kk][tx*4];
      float4 a0 = *(const float4*)&At[kk][ty*4];
      float4 a1 = *(const float4*)&At[kk][64+ty*4];
      float av[8] = {a0.x,a0.y,a0.z,a0.w,a1.x,a1.y,a1.z,a1.w};
      float xw[4] = {xv.x,xv.y,xv.z,xv.w};
#pragma unroll
      for (int r=0;r<8;++r)
#pragma unroll
        for (int c=0;c<4;++c) acc[r][c] = fmaf(av[r], xw[c], acc[r][c]);
    }
    __syncthreads();
  }
#pragma unroll
  for (int half=0; half<2; ++half)
#pragma unroll
    for (int i=0;i<4;++i){
      int row = n0 + half*64 + ty*4 + i;
      float4 v; v.x=acc[half*4+i][0]; v.y=acc[half*4+i][1];
      v.z=acc[half*4+i][2]; v.w=acc[half*4+i][3];
      *(float4*)&Y[base + (long)row*64 + tx*4] = v;
    }
}

// ---------------------------------------------------------------------------
// gemm2x (fused x-gather): Ax0T[n][q] = sum_m A[n,m]*x[q>>1, m, q&1]
// grid (16, 24), block 256, f32 out
__global__ __launch_bounds__(256) void gemm2x(const float* __restrict__ A,
    const float* __restrict__ x, float* __restrict__ Y)
{
  __shared__ float As[64][65];
  __shared__ float Xs[64][65];
  int n0 = blockIdx.x*64;
  int q0 = blockIdx.y*64;
  int tid = threadIdx.x, c = tid & 63, rq = tid >> 6;
  float acc[16];
#pragma unroll
  for (int j=0;j<16;++j) acc[j]=0.f;
  for (int m0=0; m0<1024; m0+=64){
#pragma unroll
    for (int j=0;j<16;++j){
      int idx = tid + j*256;
      int r = idx>>6, k = idx&63;
      As[r][k] = A[(size_t)(n0+r)*1024 + m0 + k];
      int qg = q0 + k;
      Xs[r][k] = x[(size_t)(qg>>1)*2048 + (size_t)(m0+r)*2 + (qg&1)];
    }
    __syncthreads();
    for (int k=0;k<64;++k){
      float xv = Xs[k][c];
#pragma unroll
      for (int j=0;j<16;++j) acc[j] = fmaf(As[rq+4*j][k], xv, acc[j]);
    }
    __syncthreads();
  }
#pragma unroll
  for (int j=0;j<16;++j)
    Y[(size_t)(n0+rq+4*j)*1536 + q0 + c] = acc[j];
}

// ---------------------------------------------------------------------------
// Gate v2 (f32, on-the-fly combine, 4bl x 4o register tile).
// zr = sigmoid(b + W^T inp); zh = z*h (o<64), rb = r (o>=64).
// grid (1024, 2), block 256.  L=0: KI=132 CH=44; L=1: KI=256 CH=32.
template<int L>
__global__ __launch_bounds__(256) void k_gate2(
    const float* __restrict__ Wg, const float* __restrict__ bgp,
    const float* __restrict__ E,
    const float* __restrict__ xsrc, const float* __restrict__ Axt,
    const float* __restrict__ h, const float* __restrict__ Ah,
    float* __restrict__ zh, float* __restrict__ rb, int t, int first)
{
  constexpr int IX  = (L==0)?2:64;
  constexpr int KI  = 2*(IX+64);
  constexpr int CH  = (L==0)?44:32;
  constexpr int NCH = KI/CH;
  constexpr int O   = 128;
  __shared__ float inp[32][KI];
  __shared__ float Wl[CH][O];
  __shared__ float En[10];
  int n = blockIdx.x, b0 = blockIdx.y*32, tid = threadIdx.x;

  if (tid < 10) En[tid] = E[n*10 + tid];
  for (int idx=tid; idx<32*IX; idx+=256){
    int bl = idx/IX, i = idx - bl*IX; int b = b0+bl;
    inp[bl][i] = (L==0)
      ? xsrc[(size_t)((b*12+t)*1024+n)*2 + i]
      : xsrc[((size_t)b<<16) + (size_t)n*64 + i];
  }
  for (int idx=tid; idx<2048; idx+=256){
    int bl = idx>>6, c = idx&63; int b = b0+bl;
    inp[bl][IX+c] = first ? 0.f : h[((size_t)b<<16) + (size_t)n*64 + c];
  }
  for (int idx=tid; idx<32*IX; idx+=256){
    int bl = idx/IX, i = idx - bl*IX; int b = b0+bl;
    inp[bl][IX+64+i] = (L==0)
      ? Axt[(size_t)n*1536 + (size_t)(b*12+t)*2 + i]
      : Axt[((size_t)b<<16) + (size_t)n*64 + i];
  }
  for (int idx=tid; idx<2048; idx+=256){
    int bl = idx>>6, c = idx&63; int b = b0+bl;
    inp[bl][2*IX+64+c] = first ? 0.f : Ah[((size_t)b<<16) + (size_t)n*64 + c];
  }
  __syncthreads();

  int bg = tid >> 5;        // 0..7 -> batches bg*4..bg*4+3
  int og = tid & 31;        // outputs og*4..og*4+3
  float acc[4][4];
#pragma unroll
  for (int d=0;d<4;++d){
    int o = og*4+d;
    float a = 0.f;
#pragma unroll
    for (int e=0;e<10;++e) a = fmaf(En[e], bgp[e*O+o], a);
#pragma unroll
    for (int bl=0;bl<4;++bl) acc[bl][d] = a;
  }

  for (int ch=0; ch<NCH; ++ch){
    for (int idx=tid; idx<CH*O; idx+=256){
      int i = idx>>7, o = idx&127;
      float a = 0.f;
#pragma unroll
      for (int e=0;e<10;++e)
        a = fmaf(En[e], Wg[((size_t)e*KI + ch*CH + i)*O + o], a);
      Wl[i][o] = a;
    }
    __syncthreads();
    for (int i=0; i<CH; i+=4){
      float4 xq[4], wq[4];
#pragma unroll
      for (int bl=0;bl<4;++bl) xq[bl] = *(const float4*)&inp[bg*4+bl][ch*CH+i];
#pragma unroll
      for (int ii=0;ii<4;++ii) wq[ii] = *(const float4*)&Wl[i+ii][og*4];
      float xv[4][4], wv[4][4];
#pragma unroll
      for (int bl=0;bl<4;++bl){ xv[bl][0]=xq[bl].x; xv[bl][1]=xq[bl].y; xv[bl][2]=xq[bl].z; xv[bl][3]=xq[bl].w; }
#pragma unroll
      for (int ii=0;ii<4;++ii){ wv[ii][0]=wq[ii].x; wv[ii][1]=wq[ii].y; wv[ii][2]=wq[ii].z; wv[ii][3]=wq[ii].w; }
#pragma unroll
      for (int bl=0;bl<4;++bl)
#pragma unroll
        for (int d=0;d<4;++d)
#pragma unroll
          for (int ii=0;ii<4;++ii)
            acc[bl][d] = fmaf(xv[bl][ii], wv[ii][d], acc[bl][d]);
    }
    __syncthreads();
  }

#pragma unroll
  for (int bl=0;bl<4;++bl){
    int b = b0 + bg*4 + bl;
    size_t base = ((size_t)b<<16) + (size_t)n*64;
#pragma unroll
    for (int d=0;d<4;++d){
      int o = og*4 + d;
      float s = 1.f/(1.f+__expf(-acc[bl][d]));
      if (o < 64){
        if (!first) zh[base+o] = s * h[base+o];
      } else {
        rb[base+o-64] = s;
      }
    }
  }
}

// ---------------------------------------------------------------------------
// Update v2 (f32, on-the-fly combine, 4bl x 2o register tile).
// hc = tanh(b + W^T inp); h = r*h + (1-r)*hc.
// grid (1024, 2), block 256.  L=0: KI=132 CH=44; L=1: KI=256 CH=64.
template<int L>
__global__ __launch_bounds__(256) void k_upd2(
    const float* __restrict__ Wu, const float* __restrict__ bup,
    const float* __restrict__ E,
    const float* __restrict__ xsrc, const float* __restrict__ Axt,
    const float* __restrict__ zh, const float* __restrict__ Azh,
    const float* __restrict__ rb, float* __restrict__ h, int t, int first)
{
  constexpr int IX  = (L==0)?2:64;
  constexpr int KI  = 2*(IX+64);
  constexpr int CH  = (L==0)?44:64;
  constexpr int NCH = KI/CH;
  constexpr int O   = 64;
  __shared__ float inp[32][KI];
  __shared__ float Wl[CH][O];
  __shared__ float En[10];
  int n = blockIdx.x, b0 = blockIdx.y*32, tid = threadIdx.x;

  if (tid < 10) En[tid] = E[n*10 + tid];
  for (int idx=tid; idx<32*IX; idx+=256){
    int bl = idx/IX, i = idx - bl*IX; int b = b0+bl;
    inp[bl][i] = (L==0)
      ? xsrc[(size_t)((b*12+t)*1024+n)*2 + i]
      : xsrc[((size_t)b<<16) + (size_t)n*64 + i];
  }
  for (int idx=tid; idx<2048; idx+=256){
    int bl = idx>>6, c = idx&63; int b = b0+bl;
    inp[bl][IX+c] = first ? 0.f : zh[((size_t)b<<16) + (size_t)n*64 + c];
  }
  for (int idx=tid; idx<32*IX; idx+=256){
    int bl = idx/IX, i = idx - bl*IX; int b = b0+bl;
    inp[bl][IX+64+i] = (L==0)
      ? Axt[(size_t)n*1536 + (size_t)(b*12+t)*2 + i]
      : Axt[((size_t)b<<16) + (size_t)n*64 + i];
  }
  for (int idx=tid; idx<2048; idx+=256){
    int bl = idx>>6, c = idx&63; int b = b0+bl;
    inp[bl][2*IX+64+c] = first ? 0.f : Azh[((size_t)b<<16) + (size_t)n*64 + c];
  }
  __syncthreads();

  int bg = tid >> 5;        // 0..7
  int og = tid & 31;        // outputs og*2, og*2+1
  float acc[4][2];
#pragma unroll
  for (int d=0;d<2;++d){
    int o = og*2+d;
    float a = 0.f;
#pragma unroll
    for (int e=0;e<10;++e) a = fmaf(En[e], bup[e*O+o], a);
#pragma unroll
    for (int bl=0;bl<4;++bl) acc[bl][d] = a;
  }

  for (int ch=0; ch<NCH; ++ch){
    for (int idx=tid; idx<CH*O; idx+=256){
      int i = idx>>6, o = idx&63;
      float a = 0.f;
#pragma unroll
      for (int e=0;e<10;++e)
        a = fmaf(En[e], Wu[((size_t)e*KI + ch*CH + i)*O + o], a);
      Wl[i][o] = a;
    }
    __syncthreads();
    for (int i=0; i<CH; i+=4){
      float4 xq[4]; float2 wq[4];
#pragma unroll
      for (int bl=0;bl<4;++bl) xq[bl] = *(const float4*)&inp[bg*4+bl][ch*CH+i];
#pragma unroll
      for (int ii=0;ii<4;++ii) wq[ii] = *(const float2*)&Wl[i+ii][og*2];
      float xv[4][4], wv[4][2];
#pragma unroll
      for (int bl=0;bl<4;++bl){ xv[bl][0]=xq[bl].x; xv[bl][1]=xq[bl].y; xv[bl][2]=xq[bl].z; xv[bl][3]=xq[bl].w; }
#pragma unroll
      for (int ii=0;ii<4;++ii){ wv[ii][0]=wq[ii].x; wv[ii][1]=wq[ii].y; }
#pragma unroll
      for (int bl=0;bl<4;++bl)
#pragma unroll
        for (int d=0;d<2;++d)
#pragma unroll
          for (int ii=0;ii<4;++ii)
            acc[bl][d] = fmaf(xv[bl][ii], wv[ii][d], acc[bl][d]);
    }
    __syncthreads();
  }

#pragma unroll
  for (int bl=0;bl<4;++bl){
    int b = b0 + bg*4 + bl;
    size_t base = ((size_t)b<<16) + (size_t)n*64;
#pragma unroll
    for (int d=0;d<2;++d){
      int o = og*2 + d;
      float hc = tanhf(acc[bl][d]);
      float r  = rb[base+o];
      float h0v = first ? 0.f : h[base+o];
      h[base+o] = r*h0v + (1.f-r)*hc;
    }
  }
}

// ---------------------------------------------------------------------------
// q1acc[b,n,i] (+)= sum_c h1[b,n,c] * V[i,t,c]   grid (1024), block 256
__global__ __launch_bounds__(256) void k_q1t(const float* __restrict__ h1,
    const float* __restrict__ V, float* __restrict__ q1acc, int t, int first)
{
  __shared__ float VL[12][64];
  int n = blockIdx.x, tid = threadIdx.x;
  for (int idx=tid; idx<768; idx+=256){
    int i = idx>>6, c = idx&63;
    VL[i][c] = V[(i*12+t)*64 + c];
  }
  __syncthreads();
  for (int task=tid; task<768; task+=256){
    int b = task/12, i = task - (task/12)*12;
    const float* hv = h1 + ((size_t)b<<16) + (size_t)n*64;
    float s = 0.f;
#pragma unroll
    for (int c=0;c<64;++c) s = fmaf(hv[c], VL[i][c], s);
    size_t qi = (((size_t)b<<10) + n)*12 + i;
    if (first) q1acc[qi] = s; else q1acc[qi] += s;
  }
}

// ---------------------------------------------------------------------------
// q0buf[b,n,i] = sum_{ip,c} rel[b,ip,c]*(G[i,ip,2c]+dA*G[i,ip,2c+1])
// grid 1024, block 256
__global__ __launch_bounds__(256) void k_q0G(
    const float* __restrict__ x, const float* __restrict__ diagA,
    const u16* __restrict__ G,
    const float* __restrict__ Wr, const float* __restrict__ br,
    float* __restrict__ q0buf)
{
  int n = blockIdx.x, tid = threadIdx.x;
  __shared__ u16  GL[18432];
  __shared__ float xsL[64][24];
  __shared__ float WrL[64][2];
  __shared__ float brL[64];

  for (int idx=tid; idx<18432; idx+=256) GL[idx] = G[idx];
  for (int idx=tid; idx<1536; idx+=256){
    int b = idx/24, r = idx - b*24;
    xsL[b][r] = x[(size_t)((b*12+(r>>1))*1024+n)*2 + (r&1)];
  }
  if (tid<128) WrL[tid>>1][tid&1] = Wr[tid];
  else if (tid<192) brL[tid-128] = br[tid-128];
  __syncthreads();

  float dA = diagA[n];
  int b = tid & 63, iq = tid >> 6;
  int i0 = iq*3;
  float q0a=0.f, q0b=0.f, q0c=0.f;
  for (int ip=0; ip<12; ++ip){
    float xa = xsL[b][ip*2], xb = xsL[b][ip*2+1];
    const u16* g0r = &GL[((i0+0)*12+ip)*128];
    const u16* g1r = &GL[((i0+1)*12+ip)*128];
    const u16* g2r = &GL[((i0+2)*12+ip)*128];
    for (int c=0;c<64;++c){
      float rel  = fmaf(xa, WrL[c][0], fmaf(xb, WrL[c][1], brL[c]));
      float relD = rel * dA;
      u32 g0 = *(const u32*)&g0r[2*c];
      u32 g1 = *(const u32*)&g1r[2*c];
      u32 g2 = *(const u32*)&g2r[2*c];
      q0a = fmaf(rel, bf2f((u16)g0), fmaf(relD, bf2f((u16)(g0>>16)), q0a));
      q0b = fmaf(rel, bf2f((u16)g1), fmaf(relD, bf2f((u16)(g1>>16)), q0b));
      q0c = fmaf(rel, bf2f((u16)g2), fmaf(relD, bf2f((u16)(g2>>16)), q0c));
    }
  }
  size_t qb = (((size_t)b<<10) + n)*12;
  q0buf[qb+i0]   = q0a;
  q0buf[qb+i0+1] = q0b;
  q0buf[qb+i0+2] = q0c;
}

// ---------------------------------------------------------------------------
// out[b,o,n] = b3eff[o] + sum_i q0*W3[o,i,0] + q1*W3[o,i,1]   grid 1024
__global__ __launch_bounds__(256) void k_head2(
    const float* __restrict__ q0buf, const float* __restrict__ q1acc,
    const float* __restrict__ W3, const float* __restrict__ b3eff,
    float* __restrict__ out)
{
  int n = blockIdx.x, tid = threadIdx.x;
  __shared__ float W3L[12][12][2];
  __shared__ float b3eL[12];
  __shared__ float q0L[64][12];
  __shared__ float q1L[64][12];

  if (tid < 12) b3eL[tid] = b3eff[tid];
  for (int idx=tid; idx<288; idx+=256){
    int o = idx/24, r = idx - o*24;
    W3L[o][r>>1][r&1] = W3[idx];
  }
  for (int idx=tid; idx<768; idx+=256){
    int b = idx/12, i = idx - (idx/12)*12;
    size_t base = (((size_t)b<<10) + n)*12 + i;
    q0L[b][i] = q0buf[base];
    q1L[b][i] = q1acc[base];
  }
  __syncthreads();

  for (int idx=tid; idx<768; idx+=256){
    int bb = idx/12, o = idx - (idx/12)*12;
    float a = b3eL[o];
#pragma unroll
    for (int i=0;i<12;++i)
      a += q0L[bb][i]*W3L[o][i][0] + q1L[bb][i]*W3L[o][i][1];
    out[(size_t)(bb*12+o)*1024 + n] = a;
  }
}

// ---------------------------------------------------------------------------
extern "C" void kernel_launch(void* const* d_in, const int* in_sizes, int n_in,
                              void* d_out, int out_size, void* d_ws, size_t ws_size,
                              hipStream_t stream)
{
  const float* x   = (const float*)d_in[0];
  const float* E   = (const float*)d_in[1];
  const float* Wg0 = (const float*)d_in[2];
  const float* bg0 = (const float*)d_in[3];
  const float* Wu0 = (const float*)d_in[4];
  const float* bu0 = (const float*)d_in[5];
  const float* Wg1 = (const float*)d_in[6];
  const float* bg1 = (const float*)d_in[7];
  const float* Wu1 = (const float*)d_in[8];
  const float* bu1 = (const float*)d_in[9];
  const float* Wr  = (const float*)d_in[10];
  const float* br  = (const float*)d_in[11];
  const float* W1  = (const float*)d_in[12];
  const float* Wc  = (const float*)d_in[13];
  const float* W2  = (const float*)d_in[14];
  const float* b2  = (const float*)d_in[15];
  const float* W3  = (const float*)d_in[16];
  const float* b3  = (const float*)d_in[17];

  char* ws = (char*)d_ws;
  size_t off = 0;
  auto alloc = [&](size_t bytes)->void*{
    void* p = ws + off; off += (bytes + 255) & ~(size_t)255; return p;
  };
  float* A     = (float*)alloc(1024ull*1024*4);
  float* diagA = (float*)alloc(1024*4);
  float* Ax0T  = (float*)alloc(1024ull*1536*4);
  float* AhZ0  = (float*)alloc(64ull*65536*4);
  float* AhZ1  = (float*)alloc(64ull*65536*4);
  float* zh    = (float*)alloc(64ull*65536*4);
  float* rb    = (float*)alloc(64ull*65536*4);
  float* Axt1  = (float*)alloc(64ull*65536*4);
  float* h0    = (float*)alloc(64ull*65536*4);
  float* h1    = (float*)alloc(64ull*65536*4);
  float* q1acc = (float*)alloc(64ull*1024*12*4);
  float* q0buf = (float*)alloc(64ull*1024*12*4);
  float* V     = (float*)alloc(12ull*12*64*4);
  u16*   G     = (u16*)alloc(12ull*12*128*2);
  float* b3eff = (float*)alloc(12*4);

  if (off > ws_size) return;   // clean fail instead of fault

  // ---- precomputes ----
  k_A2<<<dim3(1024),256,0,stream>>>(E, A, diagA);
  k_b3eff<<<dim3(1),64,0,stream>>>(b2, W3, b3, b3eff);
  k_Vpre<<<dim3(36),256,0,stream>>>(W1, W2, V);
  k_Gpre<<<dim3(72),256,0,stream>>>(Wc, W2, G);
  gemm2x<<<dim3(16,24),256,0,stream>>>(A, x, Ax0T);
  k_q0G<<<dim3(1024),256,0,stream>>>(x, diagA, G, Wr, br, q0buf);

  for (int t=0;t<12;++t){
    int first = (t==0);
    // ---- layer 0 (Ah := Axt1 from previous step's A@h0) ----
    k_gate2<0><<<dim3(1024,2),256,0,stream>>>(Wg0, bg0, E, x, Ax0T, h0, Axt1,
                                              zh, rb, t, first);
    if (!first) gemm3f<<<dim3(8,64),256,0,stream>>>(A, zh, AhZ0);
    k_upd2<0><<<dim3(1024,2),256,0,stream>>>(Wu0, bu0, E, x, Ax0T, zh, AhZ0,
                                             rb, h0, t, first);
    // ---- layer 1 ----
    gemm3f<<<dim3(8,64),256,0,stream>>>(A, h0, Axt1);
    if (!first) gemm3f<<<dim3(8,64),256,0,stream>>>(A, h1, AhZ1);
    k_gate2<1><<<dim3(1024,2),256,0,stream>>>(Wg1, bg1, E, h0, Axt1, h1, AhZ1,
                                              zh, rb, t, first);
    if (!first) gemm3f<<<dim3(8,64),256,0,stream>>>(A, zh, AhZ0);
    k_upd2<1><<<dim3(1024,2),256,0,stream>>>(Wu1, bu1, E, h0, Axt1, zh, AhZ0,
                                             rb, h1, t, first);
    k_q1t<<<dim3(1024),256,0,stream>>>(h1, V, q1acc, t, first);
  }

  // ---- output head ----
  k_head2<<<dim3(1024),256,0,stream>>>(q0buf, q1acc, W3, b3eff, (float*)d_out);
}

// Round 10
// 10477.902 us; speedup vs baseline: 5.3308x; 1.0301x over previous
//
#include <hip/hip_runtime.h>

typedef unsigned short u16;
typedef unsigned int   u32;

// B=64, T=12, N=1024, DIN=2, HID=64, ED=10, K=2
// f32 recurrence throughout (bf16 on the recurrent path amplifies ~x100).
__device__ __forceinline__ float bf2f(u16 u){ return __uint_as_float(((u32)u)<<16); }
__device__ __forceinline__ u16 f2bf(float f){
  u32 u = __float_as_uint(f);
  return (u16)((u + 0x7fffu + ((u>>16)&1u)) >> 16);
}

// ---------------------------------------------------------------------------
// A = softmax(relu(E E^T), axis=1); writes row-major A, col-major At, diagA.
// grid 1024, block 256
__global__ __launch_bounds__(256) void k_A2(const float* __restrict__ E,
    float* __restrict__ A, float* __restrict__ At, float* __restrict__ diagA)
{
  __shared__ float EL[10][1024];
  __shared__ float row[1024];
  __shared__ float red[4];
  int n = blockIdx.x, tid = threadIdx.x;
  for (int idx=tid; idx<10240; idx+=256)
    EL[idx>>10][idx&1023] = E[(idx&1023)*10 + (idx>>10)];
  __syncthreads();
  float en[10];
#pragma unroll
  for (int e=0;e<10;++e) en[e] = EL[e][n];
  float lmax = -1e30f;
#pragma unroll
  for (int j=0;j<4;++j){
    int m = tid*4 + j;
    float d = 0.f;
#pragma unroll
    for (int e=0;e<10;++e) d = fmaf(en[e], EL[e][m], d);
    d = fmaxf(d, 0.f);
    row[m] = d; lmax = fmaxf(lmax, d);
  }
#pragma unroll
  for (int o=32;o>0;o>>=1) lmax = fmaxf(lmax, __shfl_xor(lmax, o));
  if ((tid&63)==0) red[tid>>6] = lmax;
  __syncthreads();
  float mx = fmaxf(fmaxf(red[0],red[1]), fmaxf(red[2],red[3]));
  __syncthreads();
  float lsum = 0.f;
#pragma unroll
  for (int j=0;j<4;++j){
    int m = tid*4 + j;
    float ex = expf(row[m] - mx);
    row[m] = ex; lsum += ex;
  }
#pragma unroll
  for (int o=32;o>0;o>>=1) lsum += __shfl_xor(lsum, o);
  if ((tid&63)==0) red[tid>>6] = lsum;
  __syncthreads();
  float inv = 1.f/(red[0]+red[1]+red[2]+red[3]);
#pragma unroll
  for (int j=0;j<4;++j){
    int m = tid*4 + j;
    float v = row[m]*inv;
    A[(size_t)n*1024 + m]  = v;
    At[(size_t)m*1024 + n] = v;
    if (m == n) diagA[n] = v;
  }
}

// ---------------------------------------------------------------------------
// b3eff[o] = b3[o] + sum_i b2[i]*(W3[o,i,0]+W3[o,i,1])
__global__ __launch_bounds__(64) void k_b3eff(
    const float* __restrict__ b2, const float* __restrict__ W3,
    const float* __restrict__ b3, float* __restrict__ b3eff)
{
  int o = threadIdx.x;
  if (o < 12){
    float a = b3[o];
    for (int i=0;i<12;++i)
      a += b2[i] * (W3[(o*12+i)*2] + W3[(o*12+i)*2+1]);
    b3eff[o] = a;
  }
}

// ---------------------------------------------------------------------------
// V[i,j,c] = sum_o W2[i,j,o]*W1[o,c]  (f32)  grid 36, block 256
__global__ __launch_bounds__(256) void k_Vpre(const float* __restrict__ W1,
    const float* __restrict__ W2, float* __restrict__ V)
{
  int idx = blockIdx.x*256 + threadIdx.x;      // < 9216
  if (idx >= 9216) return;
  int c = idx & 63, r = idx >> 6;
  int j = r % 12, i = r / 12;
  float a = 0.f;
  for (int o=0;o<64;++o)
    a = fmaf(W2[(i*12+j)*64+o], W1[o*64+c], a);
  V[idx] = a;
}

// ---------------------------------------------------------------------------
// G[i,ip,u] = sum_j sum_w W2[i,j,w]*Wc[j,ip,u-w]  (bf16)  grid 72, block 256
__global__ __launch_bounds__(256) void k_Gpre(const float* __restrict__ Wc,
    const float* __restrict__ W2, u16* __restrict__ G)
{
  int idx = blockIdx.x*256 + threadIdx.x;      // < 18432
  int u = idx & 127, r = idx >> 7;
  int ip = r % 12, i = r / 12;
  float a = 0.f;
  int wlo = u>64 ? u-64 : 0;
  int whi = u<63 ? u : 63;
  for (int j=0;j<12;++j){
    const float* w2r = W2 + (i*12+j)*64;
    const float* wcr = Wc + (j*12+ip)*65;
    for (int w=wlo; w<=whi; ++w)
      a = fmaf(w2r[w], wcr[u-w], a);
  }
  G[idx] = f2bf(a);
}

// ---------------------------------------------------------------------------
// gemm4: Y[n][c] = sum_m At[m][n]*X[m][c]  (f32, 128x64 tile, K-chunk 32)
// grid (8, 64, NZ): z=0 -> (X0,Y0), z=1 -> (X1,Y1).  block 256.
__global__ __launch_bounds__(256) void gemm4(const float* __restrict__ At,
    const float* __restrict__ X0, float* __restrict__ Y0,
    const float* __restrict__ X1, float* __restrict__ Y1)
{
  const float* X = blockIdx.z ? X1 : X0;
  float*       Y = blockIdx.z ? Y1 : Y0;
  int n0 = blockIdx.x * 128;
  long base = (long)blockIdx.y * 65536;
  __shared__ float Al[32*128];   // Al[k][nl] linear
  __shared__ float Xl[32*64];    // Xl[k][c]  linear
  int tid = threadIdx.x;
  int tx = tid & 15, ty = tid >> 4;    // tx: col quad, ty: row quad (0..15)
  float acc[8][4];
#pragma unroll
  for (int r=0;r<8;++r){ acc[r][0]=0;acc[r][1]=0;acc[r][2]=0;acc[r][3]=0; }

  for (int m0=0; m0<1024; m0+=32){
    // stage A: 32 k-rows x 128 n — contiguous copy (At is col-major)
#pragma unroll
    for (int i=0;i<4;++i){
      int fo = tid + i*256;             // float4 index, 0..1023
      int k = fo >> 5, nl4 = fo & 31;
      float4 v = *(const float4*)(At + (size_t)(m0+k)*1024 + n0 + nl4*4);
      *(float4*)(Al + fo*4) = v;
    }
    // stage X: 32 k-rows x 64 c — contiguous copy
#pragma unroll
    for (int i=0;i<2;++i){
      int fo = tid + i*256;             // 0..511
      float4 v = *(const float4*)(X + base + (long)m0*64 + fo*4);
      *(float4*)(Xl + fo*4) = v;
    }
    __syncthreads();
#pragma unroll
    for (int kk=0;kk<32;++kk){
      float4 xv = *(const float4*)(Xl + kk*64 + tx*4);
      float4 a0 = *(const float4*)(Al + kk*128 + ty*4);
      float4 a1 = *(const float4*)(Al + kk*128 + 64 + ty*4);
      float av[8] = {a0.x,a0.y,a0.z,a0.w,a1.x,a1.y,a1.z,a1.w};
      float xw[4] = {xv.x,xv.y,xv.z,xv.w};
#pragma unroll
      for (int r=0;r<8;++r)
#pragma unroll
        for (int c=0;c<4;++c) acc[r][c] = fmaf(av[r], xw[c], acc[r][c]);
    }
    __syncthreads();
  }
#pragma unroll
  for (int half=0; half<2; ++half)
#pragma unroll
    for (int i=0;i<4;++i){
      int row = n0 + half*64 + ty*4 + i;
      float4 v; v.x=acc[half*4+i][0]; v.y=acc[half*4+i][1];
      v.z=acc[half*4+i][2]; v.w=acc[half*4+i][3];
      *(float4*)&Y[base + (long)row*64 + tx*4] = v;
    }
}

// ---------------------------------------------------------------------------
// gemm2x (fused x-gather): Ax0T[n][q] = sum_m A[n,m]*x[q>>1, m, q&1]
// grid (16, 24), block 256, f32 out  (one-shot precompute; row-major A)
__global__ __launch_bounds__(256) void gemm2x(const float* __restrict__ A,
    const float* __restrict__ x, float* __restrict__ Y)
{
  __shared__ float As[64][65];
  __shared__ float Xs[64][65];
  int n0 = blockIdx.x*64;
  int q0 = blockIdx.y*64;
  int tid = threadIdx.x, c = tid & 63, rq = tid >> 6;
  float acc[16];
#pragma unroll
  for (int j=0;j<16;++j) acc[j]=0.f;
  for (int m0=0; m0<1024; m0+=64){
#pragma unroll
    for (int j=0;j<16;++j){
      int idx = tid + j*256;
      int r = idx>>6, k = idx&63;
      As[r][k] = A[(size_t)(n0+r)*1024 + m0 + k];
      int qg = q0 + k;
      Xs[r][k] = x[(size_t)(qg>>1)*2048 + (size_t)(m0+r)*2 + (qg&1)];
    }
    __syncthreads();
    for (int k=0;k<64;++k){
      float xv = Xs[k][c];
#pragma unroll
      for (int j=0;j<16;++j) acc[j] = fmaf(As[rq+4*j][k], xv, acc[j]);
    }
    __syncthreads();
  }
#pragma unroll
  for (int j=0;j<16;++j)
    Y[(size_t)(n0+rq+4*j)*1536 + q0 + c] = acc[j];
}

// ---------------------------------------------------------------------------
// Gate (f32, on-the-fly combine, 4bl x 4o register tile).
// zr = sigmoid(b + W^T inp); zh = z*h (o<64), rb = r (o>=64).
// grid (1024, 2), block 256.  L=0: KI=132 CH=44; L=1: KI=256 CH=32.
template<int L>
__global__ __launch_bounds__(256) void k_gate2(
    const float* __restrict__ Wg, const float* __restrict__ bgp,
    const float* __restrict__ E,
    const float* __restrict__ xsrc, const float* __restrict__ Axt,
    const float* __restrict__ h, const float* __restrict__ Ah,
    float* __restrict__ zh, float* __restrict__ rb, int t, int first)
{
  constexpr int IX  = (L==0)?2:64;
  constexpr int KI  = 2*(IX+64);
  constexpr int CH  = (L==0)?44:32;
  constexpr int NCH = KI/CH;
  constexpr int O   = 128;
  __shared__ float inp[32][KI];
  __shared__ float Wl[CH][O];
  __shared__ float En[10];
  int n = blockIdx.x, b0 = blockIdx.y*32, tid = threadIdx.x;

  if (tid < 10) En[tid] = E[n*10 + tid];
  for (int idx=tid; idx<32*IX; idx+=256){
    int bl = idx/IX, i = idx - bl*IX; int b = b0+bl;
    inp[bl][i] = (L==0)
      ? xsrc[(size_t)((b*12+t)*1024+n)*2 + i]
      : xsrc[((size_t)b<<16) + (size_t)n*64 + i];
  }
  for (int idx=tid; idx<2048; idx+=256){
    int bl = idx>>6, c = idx&63; int b = b0+bl;
    inp[bl][IX+c] = first ? 0.f : h[((size_t)b<<16) + (size_t)n*64 + c];
  }
  for (int idx=tid; idx<32*IX; idx+=256){
    int bl = idx/IX, i = idx - bl*IX; int b = b0+bl;
    inp[bl][IX+64+i] = (L==0)
      ? Axt[(size_t)n*1536 + (size_t)(b*12+t)*2 + i]
      : Axt[((size_t)b<<16) + (size_t)n*64 + i];
  }
  for (int idx=tid; idx<2048; idx+=256){
    int bl = idx>>6, c = idx&63; int b = b0+bl;
    inp[bl][2*IX+64+c] = first ? 0.f : Ah[((size_t)b<<16) + (size_t)n*64 + c];
  }
  __syncthreads();

  int bg = tid >> 5;
  int og = tid & 31;
  float acc[4][4];
#pragma unroll
  for (int d=0;d<4;++d){
    int o = og*4+d;
    float a = 0.f;
#pragma unroll
    for (int e=0;e<10;++e) a = fmaf(En[e], bgp[e*O+o], a);
#pragma unroll
    for (int bl=0;bl<4;++bl) acc[bl][d] = a;
  }

  for (int ch=0; ch<NCH; ++ch){
    for (int idx=tid; idx<CH*O; idx+=256){
      int i = idx>>7, o = idx&127;
      float a = 0.f;
#pragma unroll
      for (int e=0;e<10;++e)
        a = fmaf(En[e], Wg[((size_t)e*KI + ch*CH + i)*O + o], a);
      Wl[i][o] = a;
    }
    __syncthreads();
    for (int i=0; i<CH; i+=4){
      float4 xq[4], wq[4];
#pragma unroll
      for (int bl=0;bl<4;++bl) xq[bl] = *(const float4*)&inp[bg*4+bl][ch*CH+i];
#pragma unroll
      for (int ii=0;ii<4;++ii) wq[ii] = *(const float4*)&Wl[i+ii][og*4];
      float xv[4][4], wv[4][4];
#pragma unroll
      for (int bl=0;bl<4;++bl){ xv[bl][0]=xq[bl].x; xv[bl][1]=xq[bl].y; xv[bl][2]=xq[bl].z; xv[bl][3]=xq[bl].w; }
#pragma unroll
      for (int ii=0;ii<4;++ii){ wv[ii][0]=wq[ii].x; wv[ii][1]=wq[ii].y; wv[ii][2]=wq[ii].z; wv[ii][3]=wq[ii].w; }
#pragma unroll
      for (int bl=0;bl<4;++bl)
#pragma unroll
        for (int d=0;d<4;++d)
#pragma unroll
          for (int ii=0;ii<4;++ii)
            acc[bl][d] = fmaf(xv[bl][ii], wv[ii][d], acc[bl][d]);
    }
    __syncthreads();
  }

#pragma unroll
  for (int bl=0;bl<4;++bl){
    int b = b0 + bg*4 + bl;
    size_t base = ((size_t)b<<16) + (size_t)n*64;
#pragma unroll
    for (int d=0;d<4;++d){
      int o = og*4 + d;
      float s = 1.f/(1.f+__expf(-acc[bl][d]));
      if (o < 64){
        if (!first) zh[base+o] = s * h[base+o];
      } else {
        rb[base+o-64] = s;
      }
    }
  }
}

// ---------------------------------------------------------------------------
// Update (f32, on-the-fly combine, 4bl x 2o register tile).
// hc = tanh(b + W^T inp); h = r*h + (1-r)*hc.
// grid (1024, 2), block 256.  L=0: KI=132 CH=44; L=1: KI=256 CH=64.
template<int L>
__global__ __launch_bounds__(256) void k_upd2(
    const float* __restrict__ Wu, const float* __restrict__ bup,
    const float* __restrict__ E,
    const float* __restrict__ xsrc, const float* __restrict__ Axt,
    const float* __restrict__ zh, const float* __restrict__ Azh,
    const float* __restrict__ rb, float* __restrict__ h, int t, int first)
{
  constexpr int IX  = (L==0)?2:64;
  constexpr int KI  = 2*(IX+64);
  constexpr int CH  = (L==0)?44:64;
  constexpr int NCH = KI/CH;
  constexpr int O   = 64;
  __shared__ float inp[32][KI];
  __shared__ float Wl[CH][O];
  __shared__ float En[10];
  int n = blockIdx.x, b0 = blockIdx.y*32, tid = threadIdx.x;

  if (tid < 10) En[tid] = E[n*10 + tid];
  for (int idx=tid; idx<32*IX; idx+=256){
    int bl = idx/IX, i = idx - bl*IX; int b = b0+bl;
    inp[bl][i] = (L==0)
      ? xsrc[(size_t)((b*12+t)*1024+n)*2 + i]
      : xsrc[((size_t)b<<16) + (size_t)n*64 + i];
  }
  for (int idx=tid; idx<2048; idx+=256){
    int bl = idx>>6, c = idx&63; int b = b0+bl;
    inp[bl][IX+c] = first ? 0.f : zh[((size_t)b<<16) + (size_t)n*64 + c];
  }
  for (int idx=tid; idx<32*IX; idx+=256){
    int bl = idx/IX, i = idx - bl*IX; int b = b0+bl;
    inp[bl][IX+64+i] = (L==0)
      ? Axt[(size_t)n*1536 + (size_t)(b*12+t)*2 + i]
      : Axt[((size_t)b<<16) + (size_t)n*64 + i];
  }
  for (int idx=tid; idx<2048; idx+=256){
    int bl = idx>>6, c = idx&63; int b = b0+bl;
    inp[bl][2*IX+64+c] = first ? 0.f : Azh[((size_t)b<<16) + (size_t)n*64 + c];
  }
  __syncthreads();

  int bg = tid >> 5;
  int og = tid & 31;
  float acc[4][2];
#pragma unroll
  for (int d=0;d<2;++d){
    int o = og*2+d;
    float a = 0.f;
#pragma unroll
    for (int e=0;e<10;++e) a = fmaf(En[e], bup[e*O+o], a);
#pragma unroll
    for (int bl=0;bl<4;++bl) acc[bl][d] = a;
  }

  for (int ch=0; ch<NCH; ++ch){
    for (int idx=tid; idx<CH*O; idx+=256){
      int i = idx>>6, o = idx&63;
      float a = 0.f;
#pragma unroll
      for (int e=0;e<10;++e)
        a = fmaf(En[e], Wu[((size_t)e*KI + ch*CH + i)*O + o], a);
      Wl[i][o] = a;
    }
    __syncthreads();
    for (int i=0; i<CH; i+=4){
      float4 xq[4]; float2 wq[4];
#pragma unroll
      for (int bl=0;bl<4;++bl) xq[bl] = *(const float4*)&inp[bg*4+bl][ch*CH+i];
#pragma unroll
      for (int ii=0;ii<4;++ii) wq[ii] = *(const float2*)&Wl[i+ii][og*2];
      float xv[4][4], wv[4][2];
#pragma unroll
      for (int bl=0;bl<4;++bl){ xv[bl][0]=xq[bl].x; xv[bl][1]=xq[bl].y; xv[bl][2]=xq[bl].z; xv[bl][3]=xq[bl].w; }
#pragma unroll
      for (int ii=0;ii<4;++ii){ wv[ii][0]=wq[ii].x; wv[ii][1]=wq[ii].y; }
#pragma unroll
      for (int bl=0;bl<4;++bl)
#pragma unroll
        for (int d=0;d<2;++d)
#pragma unroll
          for (int ii=0;ii<4;++ii)
            acc[bl][d] = fmaf(xv[bl][ii], wv[ii][d], acc[bl][d]);
    }
    __syncthreads();
  }

#pragma unroll
  for (int bl=0;bl<4;++bl){
    int b = b0 + bg*4 + bl;
    size_t base = ((size_t)b<<16) + (size_t)n*64;
#pragma unroll
    for (int d=0;d<2;++d){
      int o = og*2 + d;
      float hc = tanhf(acc[bl][d]);
      float r  = rb[base+o];
      float h0v = first ? 0.f : h[base+o];
      h[base+o] = r*h0v + (1.f-r)*hc;
    }
  }
}

// ---------------------------------------------------------------------------
// q1acc[b,n,i] (+)= sum_c h1[b,n,c] * V[i,t,c]   grid (1024), block 256
__global__ __launch_bounds__(256) void k_q1t(const float* __restrict__ h1,
    const float* __restrict__ V, float* __restrict__ q1acc, int t, int first)
{
  __shared__ float VL[12][64];
  int n = blockIdx.x, tid = threadIdx.x;
  for (int idx=tid; idx<768; idx+=256){
    int i = idx>>6, c = idx&63;
    VL[i][c] = V[(i*12+t)*64 + c];
  }
  __syncthreads();
  for (int task=tid; task<768; task+=256){
    int b = task/12, i = task - (task/12)*12;
    const float* hv = h1 + ((size_t)b<<16) + (size_t)n*64;
    float s = 0.f;
#pragma unroll
    for (int c=0;c<64;++c) s = fmaf(hv[c], VL[i][c], s);
    size_t qi = (((size_t)b<<10) + n)*12 + i;
    if (first) q1acc[qi] = s; else q1acc[qi] += s;
  }
}

// ---------------------------------------------------------------------------
// q0buf[b,n,i] = sum_{ip,c} rel[b,ip,c]*(G[i,ip,2c]+dA*G[i,ip,2c+1])
// grid 1024, block 256.  xsL padded [64][25] (stride 25: gcd(25,32)=1).
__global__ __launch_bounds__(256) void k_q0G(
    const float* __restrict__ x, const float* __restrict__ diagA,
    const u16* __restrict__ G,
    const float* __restrict__ Wr, const float* __restrict__ br,
    float* __restrict__ q0buf)
{
  int n = blockIdx.x, tid = threadIdx.x;
  __shared__ u16  GL[18432];
  __shared__ float xsL[64][25];
  __shared__ float WrL[64][2];
  __shared__ float brL[64];

  for (int idx=tid; idx<18432; idx+=256) GL[idx] = G[idx];
  for (int idx=tid; idx<1536; idx+=256){
    int b = idx/24, r = idx - b*24;
    xsL[b][r] = x[(size_t)((b*12+(r>>1))*1024+n)*2 + (r&1)];
  }
  if (tid<128) WrL[tid>>1][tid&1] = Wr[tid];
  else if (tid<192) brL[tid-128] = br[tid-128];
  __syncthreads();

  float dA = diagA[n];
  int b = tid & 63, iq = tid >> 6;
  int i0 = iq*3;
  float q0a=0.f, q0b=0.f, q0c=0.f;
  for (int ip=0; ip<12; ++ip){
    float xa = xsL[b][ip*2], xb = xsL[b][ip*2+1];
    const u16* g0r = &GL[((i0+0)*12+ip)*128];
    const u16* g1r = &GL[((i0+1)*12+ip)*128];
    const u16* g2r = &GL[((i0+2)*12+ip)*128];
    for (int c=0;c<64;++c){
      float rel  = fmaf(xa, WrL[c][0], fmaf(xb, WrL[c][1], brL[c]));
      float relD = rel * dA;
      u32 g0 = *(const u32*)&g0r[2*c];
      u32 g1 = *(const u32*)&g1r[2*c];
      u32 g2 = *(const u32*)&g2r[2*c];
      q0a = fmaf(rel, bf2f((u16)g0), fmaf(relD, bf2f((u16)(g0>>16)), q0a));
      q0b = fmaf(rel, bf2f((u16)g1), fmaf(relD, bf2f((u16)(g1>>16)), q0b));
      q0c = fmaf(rel, bf2f((u16)g2), fmaf(relD, bf2f((u16)(g2>>16)), q0c));
    }
  }
  size_t qb = (((size_t)b<<10) + n)*12;
  q0buf[qb+i0]   = q0a;
  q0buf[qb+i0+1] = q0b;
  q0buf[qb+i0+2] = q0c;
}

// ---------------------------------------------------------------------------
// out[b,o,n] = b3eff[o] + sum_i q0*W3[o,i,0] + q1*W3[o,i,1]   grid 1024
__global__ __launch_bounds__(256) void k_head2(
    const float* __restrict__ q0buf, const float* __restrict__ q1acc,
    const float* __restrict__ W3, const float* __restrict__ b3eff,
    float* __restrict__ out)
{
  int n = blockIdx.x, tid = threadIdx.x;
  __shared__ float W3L[12][12][2];
  __shared__ float b3eL[12];
  __shared__ float q0L[64][12];
  __shared__ float q1L[64][12];

  if (tid < 12) b3eL[tid] = b3eff[tid];
  for (int idx=tid; idx<288; idx+=256){
    int o = idx/24, r = idx - o*24;
    W3L[o][r>>1][r&1] = W3[idx];
  }
  for (int idx=tid; idx<768; idx+=256){
    int b = idx/12, i = idx - (idx/12)*12;
    size_t base = (((size_t)b<<10) + n)*12 + i;
    q0L[b][i] = q0buf[base];
    q1L[b][i] = q1acc[base];
  }
  __syncthreads();

  for (int idx=tid; idx<768; idx+=256){
    int bb = idx/12, o = idx - (idx/12)*12;
    float a = b3eL[o];
#pragma unroll
    for (int i=0;i<12;++i)
      a += q0L[bb][i]*W3L[o][i][0] + q1L[bb][i]*W3L[o][i][1];
    out[(size_t)(bb*12+o)*1024 + n] = a;
  }
}

// ---------------------------------------------------------------------------
extern "C" void kernel_launch(void* const* d_in, const int* in_sizes, int n_in,
                              void* d_out, int out_size, void* d_ws, size_t ws_size,
                              hipStream_t stream)
{
  const float* x   = (const float*)d_in[0];
  const float* E   = (const float*)d_in[1];
  const float* Wg0 = (const float*)d_in[2];
  const float* bg0 = (const float*)d_in[3];
  const float* Wu0 = (const float*)d_in[4];
  const float* bu0 = (const float*)d_in[5];
  const float* Wg1 = (const float*)d_in[6];
  const float* bg1 = (const float*)d_in[7];
  const float* Wu1 = (const float*)d_in[8];
  const float* bu1 = (const float*)d_in[9];
  const float* Wr  = (const float*)d_in[10];
  const float* br  = (const float*)d_in[11];
  const float* W1  = (const float*)d_in[12];
  const float* Wc  = (const float*)d_in[13];
  const float* W2  = (const float*)d_in[14];
  const float* b2  = (const float*)d_in[15];
  const float* W3  = (const float*)d_in[16];
  const float* b3  = (const float*)d_in[17];

  char* ws = (char*)d_ws;
  size_t off = 0;
  auto alloc = [&](size_t bytes)->void*{
    void* p = ws + off; off += (bytes + 255) & ~(size_t)255; return p;
  };
  float* A     = (float*)alloc(1024ull*1024*4);
  float* At    = (float*)alloc(1024ull*1024*4);
  float* diagA = (float*)alloc(1024*4);
  float* Ax0T  = (float*)alloc(1024ull*1536*4);
  float* AhZ0  = (float*)alloc(64ull*65536*4);
  float* AhZ1  = (float*)alloc(64ull*65536*4);
  float* zh    = (float*)alloc(64ull*65536*4);
  float* rb    = (float*)alloc(64ull*65536*4);
  float* Axt1  = (float*)alloc(64ull*65536*4);
  float* h0    = (float*)alloc(64ull*65536*4);
  float* h1    = (float*)alloc(64ull*65536*4);
  float* q1acc = (float*)alloc(64ull*1024*12*4);
  float* q0buf = (float*)alloc(64ull*1024*12*4);
  float* V     = (float*)alloc(12ull*12*64*4);
  u16*   G     = (u16*)alloc(12ull*12*128*2);
  float* b3eff = (float*)alloc(12*4);

  if (off > ws_size) return;   // clean fail instead of fault

  // ---- precomputes ----
  k_A2<<<dim3(1024),256,0,stream>>>(E, A, At, diagA);
  k_b3eff<<<dim3(1),64,0,stream>>>(b2, W3, b3, b3eff);
  k_Vpre<<<dim3(36),256,0,stream>>>(W1, W2, V);
  k_Gpre<<<dim3(72),256,0,stream>>>(Wc, W2, G);
  gemm2x<<<dim3(16,24),256,0,stream>>>(A, x, Ax0T);
  k_q0G<<<dim3(1024),256,0,stream>>>(x, diagA, G, Wr, br, q0buf);

  for (int t=0;t<12;++t){
    int first = (t==0);
    // ---- layer 0 (Ah := Axt1 from previous step's A@h0) ----
    k_gate2<0><<<dim3(1024,2),256,0,stream>>>(Wg0, bg0, E, x, Ax0T, h0, Axt1,
                                              zh, rb, t, first);
    if (!first) gemm4<<<dim3(8,64,1),256,0,stream>>>(At, zh, AhZ0, nullptr, nullptr);
    k_upd2<0><<<dim3(1024,2),256,0,stream>>>(Wu0, bu0, E, x, Ax0T, zh, AhZ0,
                                             rb, h0, t, first);
    // paired: z=0 -> A@h0(t) -> Axt1 ; z=1 -> A@h1(t-1) -> AhZ1
    gemm4<<<dim3(8,64, first?1:2),256,0,stream>>>(At, h0, Axt1, h1, AhZ1);
    // ---- layer 1 ----
    k_gate2<1><<<dim3(1024,2),256,0,stream>>>(Wg1, bg1, E, h0, Axt1, h1, AhZ1,
                                              zh, rb, t, first);
    if (!first) gemm4<<<dim3(8,64,1),256,0,stream>>>(At, zh, AhZ0, nullptr, nullptr);
    k_upd2<1><<<dim3(1024,2),256,0,stream>>>(Wu1, bu1, E, h0, Axt1, zh, AhZ0,
                                             rb, h1, t, first);
    k_q1t<<<dim3(1024),256,0,stream>>>(h1, V, q1acc, t, first);
  }

  // ---- output head ----
  k_head2<<<dim3(1024),256,0,stream>>>(q0buf, q1acc, W3, b3eff, (float*)d_out);
}